// Round 1
// baseline (128.546 us; speedup 1.0000x reference)
//
#include <hip/hip_runtime.h>
#include <hip/hip_fp16.h>

#define NT 256

constexpr int TABLE_SZ = 721 * 1441;

// Per-level deduplicated corner tables (each level-i cell stored ONCE).
// Entry = uint4 = {e00,e01,e10,e11} packed as __half2 feature pairs (16 B).
// Level i grid step gs=2^i over v_lat in [0,180.5], v_lon in [0,360.5]:
constexpr int H0 = 181, W0 = 361;   // level 0: lat 0..180, lon 0..360
constexpr int H1 = 91,  W1 = 181;   // level 1
constexpr int H2 = 46,  W2 = 91;    // level 2
constexpr int H3 = 23,  W3 = 46;    // level 3
constexpr int N0 = H0 * W0, N1 = H1 * W1, N2 = H2 * W2, N3 = H3 * W3;
constexpr int TOFF0 = 0, TOFF1 = N0, TOFF2 = N0 + N1, TOFF3 = N0 + N1 + N2;
constexpr int NTOT = N0 + N1 + N2 + N3;   // 87056 entries = 1.39 MB (33% of one XCD L2)

// per-(level,row) LUT: rows 181 + 91 + 46 + 23 = 341 entries of {ca, inv_n2}
constexpr int LUT_OFF0 = 0, LUT_OFF1 = 181, LUT_OFF2 = 272, LUT_OFF3 = 318;
constexpr int LUT_N = 341;

typedef float v4f __attribute__((ext_vector_type(4)));
typedef float v2f __attribute__((ext_vector_type(2)));

__device__ __constant__ float c_s2_tab[4] = {0.008726535498f, 0.017452406437f,
                                             0.034899496703f, 0.069756473744f};

__global__ __launch_bounds__(256)
void build_tables(const float* __restrict__ emb, uint4* __restrict__ tab)
{
    const int t = blockIdx.x * 256 + threadIdx.x;
    if (t >= NTOT) return;

    int lvl, ra, co;
    if (t < TOFF1)      { lvl = 0; const int i = t;         ra = i / W0; co = i - ra * W0; }
    else if (t < TOFF2) { lvl = 1; const int i = t - TOFF1; ra = i / W1; co = i - ra * W1; }
    else if (t < TOFF3) { lvl = 2; const int i = t - TOFF2; ra = i / W2; co = i - ra * W2; }
    else                { lvl = 3; const int i = t - TOFF3; ra = i / W3; co = i - ra * W3; }

    const int width = 1440 >> lvl;
    const float2* tb = (const float2*)emb + (size_t)lvl * TABLE_SZ;
    const float2 e0 = tb[ra * width + co];
    const float2 e1 = tb[ra * width + co + 1];
    const float2 e2 = tb[(ra + 1) * width + co];
    const float2 e3 = tb[(ra + 1) * width + co + 1];

    union { uint4 u; __half2 h[4]; } pk;
    pk.h[0] = __floats2half2_rn(e0.x, e0.y);
    pk.h[1] = __floats2half2_rn(e1.x, e1.y);
    pk.h[2] = __floats2half2_rn(e2.x, e2.y);
    pk.h[3] = __floats2half2_rn(e3.x, e3.y);
    tab[t] = pk.u;
}

template <bool USE_SQ>
__global__ __launch_bounds__(NT)
void ngp_interp_kernel(const float* __restrict__ x,
                       const float* __restrict__ emb,
                       const uint4* __restrict__ tab,
                       float* __restrict__ out,
                       int B)
{
    const float r = 0.017453292519943295f;   // pi/180 in fp32
    const float bmin_lat = -90.25f;
    const float bmin_lon = -0.25f;

    // ---- tiny LUT: {ca, inv_n2} per (level, lat-row); bit-identical math ----
    __shared__ float2 lut[LUT_N];
    for (int t = threadIdx.x; t < LUT_N; t += NT) {
        int lvl, row;
        if (t < LUT_OFF1)      { lvl = 0; row = t; }
        else if (t < LUT_OFF2) { lvl = 1; row = t - LUT_OFF1; }
        else if (t < LUT_OFF3) { lvl = 2; row = t - LUT_OFF2; }
        else                   { lvl = 3; row = t - LUT_OFF3; }
        const float gs = (float)(1 << lvl);
        const float gmin_lat = (float)row * gs + bmin_lat;
        const float ca = fabsf(__cosf(gmin_lat * r));
        const float z2 = ca * c_s2_tab[lvl];
        const float n2 = z2 + z2 * z2 * z2 * (1.0f / 6.0f);
        lut[t] = make_float2(ca, __builtin_amdgcn_rcpf(n2));
    }
    __syncthreads();

    const int p = blockIdx.x * NT + threadIdx.x;
    if (p >= B) return;

    const v2f xp = __builtin_nontemporal_load(reinterpret_cast<const v2f*>(x) + p);
    const float xlat = xp.x;
    const float xlon = xp.y;

    const float bmax_lat = 90.25f, bmax_lon = 360.25f;
    const float xc_lat = fminf(fmaxf(xlat, bmin_lat), bmax_lat);
    const float xc_lon = fminf(fmaxf(xlon, bmin_lon), bmax_lon);

    const float v_lat = xc_lat - bmin_lat;   // [0, 180.5]
    const float v_lon = xc_lon - bmin_lon;   // [0, 360.5]

    // ---- all four cell coords first, then issue all four gathers so the
    // weight math (LDS LUT + sin/asin series) overlaps the gather latency ----
    float blatf[4], blonf[4];
    #pragma unroll
    for (int i = 0; i < 4; ++i) {
        const float inv_gs = 1.0f / (float)(1 << i);   // pow2: mul == div exactly
        blatf[i] = floorf(v_lat * inv_gs);             // bit-identical to np
        blonf[i] = floorf(v_lon * inv_gs);
    }

    uint4 g[4];
    if (USE_SQ) {
        g[0] = tab[TOFF0 + (int)blatf[0] * W0 + (int)blonf[0]];
        g[1] = tab[TOFF1 + (int)blatf[1] * W1 + (int)blonf[1]];
        g[2] = tab[TOFF2 + (int)blatf[2] * W2 + (int)blonf[2]];
        g[3] = tab[TOFF3 + (int)blatf[3] * W3 + (int)blonf[3]];
    }

    const int lut_off[4] = {LUT_OFF0, LUT_OFF1, LUT_OFF2, LUT_OFF3};

    float o[8];

    #pragma unroll
    for (int i = 0; i < 4; ++i) {
        const float gs     = (float)(1 << i);
        const float inv_gs = 1.0f / gs;
        const int   width  = 1440 >> i;

        const float gmin_lat = blatf[i] * gs + bmin_lat;
        const float gmin_lon = blonf[i] * gs + bmin_lon;
        const float gmax_lon = gmin_lon + gs;
        const int bl_lat = (int)blatf[i];

        v2f E0, E1, E2, E3;
        if (USE_SQ) {
            union { uint4 u; __half2 h[4]; } pk;
            pk.u = g[i];
            float2 f0 = __half22float2(pk.h[0]);
            float2 f1 = __half22float2(pk.h[1]);
            float2 f2 = __half22float2(pk.h[2]);
            float2 f3 = __half22float2(pk.h[3]);
            E0 = (v2f){f0.x, f0.y}; E1 = (v2f){f1.x, f1.y};
            E2 = (v2f){f2.x, f2.y}; E3 = (v2f){f3.x, f3.y};
        } else {
            const int bl_lon = (int)blonf[i];
            const int idx00 = bl_lat * width + bl_lon;
            const float* base0 = emb + ((size_t)i * TABLE_SZ + (size_t)idx00) * 2;
            const float* base1 = base0 + (size_t)width * 2;
            v4f eA, eB;
            __builtin_memcpy(&eA, base0, 16);
            __builtin_memcpy(&eB, base1, 16);
            E0 = (v2f){eA.x, eA.y}; E1 = (v2f){eA.z, eA.w};
            E2 = (v2f){eB.x, eB.y}; E3 = (v2f){eB.z, eB.w};
        }

        // wlat: meridian geodesic ratio == (x_lat - gmin_lat) / gs
        const float wlat = (xlat - gmin_lat) * inv_gs;

        // wlon via LUT (bit-identical to inline version)
        const float2 cl = lut[lut_off[i] + bl_lat];
        const float h1 = (gmax_lon - xlon) * r * 0.5f;          // <= 0.0699 rad
        const float s1 = h1 - h1 * h1 * h1 * (1.0f / 6.0f);     // sin(h1)
        const float z1 = cl.x * s1;
        const float n1 = z1 + z1 * z1 * z1 * (1.0f / 6.0f);     // asin(z1)
        const float wlon = n1 * cl.y;

        const v2f wa = {wlat, wlat};
        const v2f wo = {wlon, wlon};
        const v2f c0 = E0 + (E2 - E0) * wa;
        const v2f c1 = E1 + (E3 - E1) * wa;
        const v2f res = c0 + (c1 - c0) * wo;
        o[2*i]   = res.x;
        o[2*i+1] = res.y;
    }

    v4f* op = reinterpret_cast<v4f*>(out + (size_t)p * 8);
    v4f lo = {o[0], o[1], o[2], o[3]};
    v4f hi = {o[4], o[5], o[6], o[7]};
    __builtin_nontemporal_store(lo, op);
    __builtin_nontemporal_store(hi, op + 1);
}

extern "C" void kernel_launch(void* const* d_in, const int* in_sizes, int n_in,
                              void* d_out, int out_size, void* d_ws, size_t ws_size,
                              hipStream_t stream)
{
    const float* x   = (const float*)d_in[0];   // (B, 2) fp32
    const float* emb = (const float*)d_in[1];   // (4, TABLE, 2) fp32
    float* out = (float*)d_out;                 // (B, 8) fp32
    const int B = in_sizes[0] / 2;
    const int grid = (B + NT - 1) / NT;

    const size_t tab_bytes = (size_t)NTOT * sizeof(uint4);   // 1.39 MB
    if (ws_size >= tab_bytes) {
        uint4* tab = (uint4*)d_ws;
        build_tables<<<(NTOT + 255) / 256, 256, 0, stream>>>(emb, tab);
        ngp_interp_kernel<true><<<grid, NT, 0, stream>>>(x, emb, tab, out, B);
    } else {
        ngp_interp_kernel<false><<<grid, NT, 0, stream>>>(x, emb, nullptr, out, B);
    }
}

// Round 2
// 120.170 us; speedup vs baseline: 1.0697x; 1.0697x over previous
//
#include <hip/hip_runtime.h>
#include <hip/hip_fp16.h>

#define NT 256
#define PPT 4

constexpr int TABLE_SZ = 721 * 1441;

// superquad: per level-0 cell, one 64 B cache line:
//   4 levels x {e0,e1,e2,e3} as __half2 (feat pairs) = 4 x uint4
constexpr int QLAT = 181, QLON = 361;      // level-0 cell index ranges
constexpr int NCELLS = QLAT * QLON;        // 65341 cells -> 4.18 MB

// per-(level,row) LUT: rows 181 + 91 + 46 + 23 = 341 entries of {ca, inv_n2}
constexpr int LUT_OFF0 = 0, LUT_OFF1 = 181, LUT_OFF2 = 272, LUT_OFF3 = 318;
constexpr int LUT_N = 341;

typedef float v4f __attribute__((ext_vector_type(4)));
typedef float v2f __attribute__((ext_vector_type(2)));

__device__ __constant__ float c_s2_tab[4] = {0.008726535498f, 0.017452406437f,
                                             0.034899496703f, 0.069756473744f};

__global__ __launch_bounds__(256)
void build_superquad(const float* __restrict__ emb, uint4* __restrict__ sq)
{
    int c = blockIdx.x * 256 + threadIdx.x;
    if (c >= NCELLS) return;
    int la = c / QLON, lo = c - la * QLON;
    const float2* embv = (const float2*)emb;
    #pragma unroll
    for (int i = 0; i < 4; ++i) {
        const int width = 1440 >> i;
        const int ra = la >> i, co = lo >> i;      // level-i cell (floor identity)
        const float2* t = embv + (size_t)i * TABLE_SZ;
        float2 e0 = t[ra * width + co];
        float2 e1 = t[ra * width + co + 1];
        float2 e2 = t[(ra + 1) * width + co];
        float2 e3 = t[(ra + 1) * width + co + 1];
        union { uint4 u; __half2 h[4]; } pk;
        pk.h[0] = __floats2half2_rn(e0.x, e0.y);
        pk.h[1] = __floats2half2_rn(e1.x, e1.y);
        pk.h[2] = __floats2half2_rn(e2.x, e2.y);
        pk.h[3] = __floats2half2_rn(e3.x, e3.y);
        sq[(size_t)c * 4 + i] = pk.u;
    }
}

// ---- main kernel: PPT points per thread, superquad gather (1 line/point) ----
__global__ __launch_bounds__(NT)
void ngp_interp_mp(const float* __restrict__ x,
                   const uint4* __restrict__ sq,
                   float* __restrict__ out,
                   int B)
{
    const float r = 0.017453292519943295f;   // pi/180 in fp32
    const float bmin_lat = -90.25f;
    const float bmin_lon = -0.25f;
    const float bmax_lat = 90.25f, bmax_lon = 360.25f;

    const int t = threadIdx.x;
    const int base = blockIdx.x * (NT * PPT) + t;

    // ---- issue all x loads FIRST: latency hides under the LUT build ----
    int pidx[PPT];
    v2f xp[PPT];
    #pragma unroll
    for (int k = 0; k < PPT; ++k) {
        const int p = base + k * NT;
        pidx[k] = p;
        const int pc = p < B ? p : B - 1;          // clamp: full-wave, safe read
        xp[k] = __builtin_nontemporal_load(reinterpret_cast<const v2f*>(x) + pc);
    }

    // ---- tiny LUT: {ca, inv_n2} per (level, lat-row); bit-identical math ----
    __shared__ float2 lut[LUT_N];
    for (int i = t; i < LUT_N; i += NT) {
        int lvl, row;
        if (i < LUT_OFF1)      { lvl = 0; row = i; }
        else if (i < LUT_OFF2) { lvl = 1; row = i - LUT_OFF1; }
        else if (i < LUT_OFF3) { lvl = 2; row = i - LUT_OFF2; }
        else                   { lvl = 3; row = i - LUT_OFF3; }
        const float gs = (float)(1 << lvl);
        const float gmin_lat = (float)row * gs + bmin_lat;
        const float ca = fabsf(__cosf(gmin_lat * r));
        const float z2 = ca * c_s2_tab[lvl];
        const float n2 = z2 + z2 * z2 * z2 * (1.0f / 6.0f);
        lut[i] = make_float2(ca, __builtin_amdgcn_rcpf(n2));
    }
    __syncthreads();

    // ---- compute cells + issue ALL gathers (4x MLP per wave) ----
    float vlat[PPT], vlon[PPT];
    uint4 g[PPT][4];
    #pragma unroll
    for (int k = 0; k < PPT; ++k) {
        const float xlat = xp[k].x;
        const float xlon = xp[k].y;
        const float xc_lat = fminf(fmaxf(xlat, bmin_lat), bmax_lat);
        const float xc_lon = fminf(fmaxf(xlon, bmin_lon), bmax_lon);
        vlat[k] = xc_lat - bmin_lat;   // [0, 180.5]
        vlon[k] = xc_lon - bmin_lon;   // [0, 360.5]
        const int cell0 = (int)floorf(vlat[k]) * QLON + (int)floorf(vlon[k]);
        const uint4* cellp = sq + (size_t)cell0 * 4;
        g[k][0] = cellp[0];
        g[k][1] = cellp[1];
        g[k][2] = cellp[2];
        g[k][3] = cellp[3];
    }

    const int lut_off[4] = {LUT_OFF0, LUT_OFF1, LUT_OFF2, LUT_OFF3};

    // ---- per-point math + store ----
    #pragma unroll
    for (int k = 0; k < PPT; ++k) {
        const float xlat = xp[k].x;
        const float xlon = xp[k].y;
        const float v_lat = vlat[k];
        const float v_lon = vlon[k];

        float o[8];
        #pragma unroll
        for (int i = 0; i < 4; ++i) {
            const float gs     = (float)(1 << i);
            const float inv_gs = 1.0f / gs;        // gs pow2: mul == div exactly

            // bl bit-identical to np: fp32 sub, exact pow2 div, floor
            const float blat_f = floorf(v_lat * inv_gs);
            const float blon_f = floorf(v_lon * inv_gs);
            const float gmin_lat = blat_f * gs + bmin_lat;
            const float gmin_lon = blon_f * gs + bmin_lon;
            const float gmax_lon = gmin_lon + gs;
            const int bl_lat = (int)blat_f;

            union { uint4 u; __half2 h[4]; } pk;
            pk.u = g[k][i];
            const float2 f0 = __half22float2(pk.h[0]);
            const float2 f1 = __half22float2(pk.h[1]);
            const float2 f2 = __half22float2(pk.h[2]);
            const float2 f3 = __half22float2(pk.h[3]);
            const v2f E0 = {f0.x, f0.y}, E1 = {f1.x, f1.y};
            const v2f E2 = {f2.x, f2.y}, E3 = {f3.x, f3.y};

            // wlat: meridian geodesic ratio == (x_lat - gmin_lat) / gs
            const float wlat = (xlat - gmin_lat) * inv_gs;

            // wlon via LUT (bit-identical to inline version)
            const float2 cl = lut[lut_off[i] + bl_lat];
            const float h1 = (gmax_lon - xlon) * r * 0.5f;       // <= 0.0699 rad
            const float s1 = h1 - h1 * h1 * h1 * (1.0f / 6.0f);  // sin(h1)
            const float z1 = cl.x * s1;
            const float n1 = z1 + z1 * z1 * z1 * (1.0f / 6.0f);  // asin(z1)
            const float wlon = n1 * cl.y;

            const v2f wa = {wlat, wlat};
            const v2f wo = {wlon, wlon};
            const v2f c0 = E0 + (E2 - E0) * wa;
            const v2f c1 = E1 + (E3 - E1) * wa;
            const v2f res = c0 + (c1 - c0) * wo;
            o[2*i]   = res.x;
            o[2*i+1] = res.y;
        }

        if (pidx[k] < B) {
            v4f* op = reinterpret_cast<v4f*>(out + (size_t)pidx[k] * 8);
            const v4f lo = {o[0], o[1], o[2], o[3]};
            const v4f hi = {o[4], o[5], o[6], o[7]};
            __builtin_nontemporal_store(lo, op);
            __builtin_nontemporal_store(hi, op + 1);
        }
    }
}

// ---- fallback (no workspace): original single-point kernel, reads emb ----
__global__ __launch_bounds__(NT)
void ngp_interp_fb(const float* __restrict__ x,
                   const float* __restrict__ emb,
                   float* __restrict__ out,
                   int B)
{
    const float r = 0.017453292519943295f;
    const float bmin_lat = -90.25f;
    const float bmin_lon = -0.25f;

    __shared__ float2 lut[LUT_N];
    for (int t = threadIdx.x; t < LUT_N; t += NT) {
        int lvl, row;
        if (t < LUT_OFF1)      { lvl = 0; row = t; }
        else if (t < LUT_OFF2) { lvl = 1; row = t - LUT_OFF1; }
        else if (t < LUT_OFF3) { lvl = 2; row = t - LUT_OFF2; }
        else                   { lvl = 3; row = t - LUT_OFF3; }
        const float gs = (float)(1 << lvl);
        const float gmin_lat = (float)row * gs + bmin_lat;
        const float ca = fabsf(__cosf(gmin_lat * r));
        const float z2 = ca * c_s2_tab[lvl];
        const float n2 = z2 + z2 * z2 * z2 * (1.0f / 6.0f);
        lut[t] = make_float2(ca, __builtin_amdgcn_rcpf(n2));
    }
    __syncthreads();

    const int p = blockIdx.x * NT + threadIdx.x;
    if (p >= B) return;

    const v2f xp = __builtin_nontemporal_load(reinterpret_cast<const v2f*>(x) + p);
    const float xlat = xp.x;
    const float xlon = xp.y;

    const float bmax_lat = 90.25f, bmax_lon = 360.25f;
    const float xc_lat = fminf(fmaxf(xlat, bmin_lat), bmax_lat);
    const float xc_lon = fminf(fmaxf(xlon, bmin_lon), bmax_lon);
    const float v_lat = xc_lat - bmin_lat;
    const float v_lon = xc_lon - bmin_lon;

    const int lut_off[4] = {LUT_OFF0, LUT_OFF1, LUT_OFF2, LUT_OFF3};
    float o[8];

    #pragma unroll
    for (int i = 0; i < 4; ++i) {
        const float gs     = (float)(1 << i);
        const float inv_gs = 1.0f / gs;
        const int   width  = 1440 >> i;

        const float blat_f = floorf(v_lat * inv_gs);
        const float blon_f = floorf(v_lon * inv_gs);
        const float gmin_lat = blat_f * gs + bmin_lat;
        const float gmin_lon = blon_f * gs + bmin_lon;
        const float gmax_lon = gmin_lon + gs;
        const int bl_lat = (int)blat_f;
        const int bl_lon = (int)blon_f;

        const int idx00 = bl_lat * width + bl_lon;
        const float* base0 = emb + ((size_t)i * TABLE_SZ + (size_t)idx00) * 2;
        const float* base1 = base0 + (size_t)width * 2;
        v4f eA, eB;
        __builtin_memcpy(&eA, base0, 16);
        __builtin_memcpy(&eB, base1, 16);
        const v2f E0 = {eA.x, eA.y}, E1 = {eA.z, eA.w};
        const v2f E2 = {eB.x, eB.y}, E3 = {eB.z, eB.w};

        const float wlat = (xlat - gmin_lat) * inv_gs;

        const float2 cl = lut[lut_off[i] + bl_lat];
        const float h1 = (gmax_lon - xlon) * r * 0.5f;
        const float s1 = h1 - h1 * h1 * h1 * (1.0f / 6.0f);
        const float z1 = cl.x * s1;
        const float n1 = z1 + z1 * z1 * z1 * (1.0f / 6.0f);
        const float wlon = n1 * cl.y;

        const v2f wa = {wlat, wlat};
        const v2f wo = {wlon, wlon};
        const v2f c0 = E0 + (E2 - E0) * wa;
        const v2f c1 = E1 + (E3 - E1) * wa;
        const v2f res = c0 + (c1 - c0) * wo;
        o[2*i]   = res.x;
        o[2*i+1] = res.y;
    }

    v4f* op = reinterpret_cast<v4f*>(out + (size_t)p * 8);
    const v4f lo = {o[0], o[1], o[2], o[3]};
    const v4f hi = {o[4], o[5], o[6], o[7]};
    __builtin_nontemporal_store(lo, op);
    __builtin_nontemporal_store(hi, op + 1);
}

extern "C" void kernel_launch(void* const* d_in, const int* in_sizes, int n_in,
                              void* d_out, int out_size, void* d_ws, size_t ws_size,
                              hipStream_t stream)
{
    const float* x   = (const float*)d_in[0];   // (B, 2) fp32
    const float* emb = (const float*)d_in[1];   // (4, TABLE, 2) fp32
    float* out = (float*)d_out;                 // (B, 8) fp32
    const int B = in_sizes[0] / 2;

    const size_t sq_bytes = (size_t)NCELLS * 64;
    if (ws_size >= sq_bytes) {
        uint4* sq = (uint4*)d_ws;
        build_superquad<<<(NCELLS + 255) / 256, 256, 0, stream>>>(emb, sq);
        const int pts_per_blk = NT * PPT;
        const int grid = (B + pts_per_blk - 1) / pts_per_blk;
        ngp_interp_mp<<<grid, NT, 0, stream>>>(x, sq, out, B);
    } else {
        const int grid = (B + NT - 1) / NT;
        ngp_interp_fb<<<grid, NT, 0, stream>>>(x, emb, out, B);
    }
}